// Round 2
// baseline (386.895 us; speedup 1.0000x reference)
//
#include <hip/hip_runtime.h>

typedef unsigned int u32;
typedef unsigned short u16;
typedef unsigned long long u64;

typedef float f32x4 __attribute__((ext_vector_type(4)));
typedef short bf16x8 __attribute__((ext_vector_type(8)));

#define B_   16
#define C_   128
#define SEQ_ 16384
#define K_   64
#define TS_  64     // samples per tile
#define NT_  8      // tiles per block
#define CHUNK_ 512  // samples per block

// ---- workspace layout (float offsets) ----
constexpr int OFF_EACC = 0;            // [B][K][C] = 131072 floats (atomic accum)
constexpr int OFF_ASUM = 131072;       // [B][K]    = 1024
constexpr int OFF_BNS  = 132096;       // [K] bn scale  (k2a -> k2b)
constexpr int OFF_BNB  = 132160;       // [K] bn bias
constexpr int OFF_SM   = 136192;       // [K]
constexpr int OFF_SMC2 = 136256;       // [K] sm[k]*||cw_k||^2 (fp32-exact)
constexpr int OFF_SCALE= 136320;       // [B][C] = 2048

__device__ __forceinline__ u16 f2bf(float f) {
    u32 b = __float_as_uint(f);
    return (u16)((b + 0x7FFFu + ((b >> 16) & 1u)) >> 16);   // RNE
}
__device__ __forceinline__ float scrub(float v) {
    return fminf(fmaxf(v, -1.0e4f), 1.0e4f);
}

// ---------------- k0: prep tables ----------------
__global__ void k0_prep(const float* __restrict__ cw, const float* __restrict__ sm,
                        float* __restrict__ ws) {
    const int t = threadIdx.x;
    if (t < K_) {
        float s2 = 0.f;
        for (int c = 0; c < C_; ++c) { float f = cw[t * C_ + c]; s2 += f * f; }
        float smv = sm[t];
        ws[OFF_SM + t] = smv;
        ws[OFF_SMC2 + t] = smv * s2;
    }
}

// ---------------- k1: MFMA soft-assign encode + aggregate ----------------
// grid = 512 blocks, 256 threads (4 waves), 3 blocks/CU (LDS 40KB, VGPR<=168)
// 2 barriers/tile software pipeline:
//   phase2(t): stage xsc(t) + prefetch(t+1) + GEMM2(t-1)
//   phase1(t): GEMM1(t) + softmax(t) + alds write
__global__ __launch_bounds__(256, 3)
void k1_encode(const float* __restrict__ xg, const float* __restrict__ cwg, float* ws) {
    __shared__ __align__(16) u16 xsc_h[TS_ * C_];   // [s][c] hi, XOR ((s&15)<<3) on c-units
    __shared__ __align__(16) u16 xsc_l[TS_ * C_];   // [s][c] lo
    __shared__ __align__(16) u16 alds[K_ * TS_];    // [k][s], XOR ((k&7)<<3) on s

    const int t    = threadIdx.x;
    const int lane = t & 63;
    const int w    = t >> 6;
    const int lk   = lane & 15;
    const int lg   = lane >> 4;
    const int b      = blockIdx.x >> 5;
    const int s_base = (blockIdx.x & 31) * CHUNK_;

    // codeword fragments (GEMM1 B-operand), bf16 RNE, register-resident
    bf16x8 cwf[4][4];
#pragma unroll
    for (int nt = 0; nt < 4; ++nt)
#pragma unroll
      for (int ks = 0; ks < 4; ++ks) {
        const float* p = cwg + (size_t)(lk + 16*nt) * C_ + 8*lg + 32*ks;
        float4 v0 = *(const float4*)p;
        float4 v1 = *(const float4*)(p + 4);
        bf16x8 f;
        f[0]=(short)f2bf(v0.x); f[1]=(short)f2bf(v0.y); f[2]=(short)f2bf(v0.z); f[3]=(short)f2bf(v0.w);
        f[4]=(short)f2bf(v1.x); f[5]=(short)f2bf(v1.y); f[6]=(short)f2bf(v1.z); f[7]=(short)f2bf(v1.w);
        cwf[nt][ks] = f;
      }
    float smk[4], smc2k[4];
#pragma unroll
    for (int nt = 0; nt < 4; ++nt) {
        smk[nt]   = ws[OFF_SM   + lk + 16*nt];
        smc2k[nt] = ws[OFF_SMC2 + lk + 16*nt];
    }

    f32x4 acc2[4][2] = {};              // GEMM2 accum, persists across all tiles
    float asacc[4] = {0.f,0.f,0.f,0.f};

    const int sm_ = t & 15;   // staging: c0 = 8*sm_
    const int sg_ = t >> 4;   // staging: s0 = 4*sg_

    // GEMM2: B operand direct from global (x is [c][s] natively), truncated bf16
    auto gemm2 = [&](int stp) {
#pragma unroll
        for (int ss = 0; ss < 2; ++ss) {
            bf16x8 aA[4];
#pragma unroll
            for (int mt = 0; mt < 4; ++mt)
                aA[mt] = *(const bf16x8*)&alds[(lk + 16*mt) * TS_ + ((8*lg + 32*ss) ^ ((lk & 7) << 3))];
#pragma unroll
            for (int n = 0; n < 2; ++n) {
                const float* xr = xg + (size_t)(b * C_ + lk + 16*(2*w + n)) * SEQ_ + stp + 8*lg + 32*ss;
                float4 v0 = *(const float4*)xr;
                float4 v1 = *(const float4*)(xr + 4);
                bf16x8 bx;
                ((u32*)&bx)[0] = (__float_as_uint(v0.x) >> 16) | (__float_as_uint(v0.y) & 0xFFFF0000u);
                ((u32*)&bx)[1] = (__float_as_uint(v0.z) >> 16) | (__float_as_uint(v0.w) & 0xFFFF0000u);
                ((u32*)&bx)[2] = (__float_as_uint(v1.x) >> 16) | (__float_as_uint(v1.y) & 0xFFFF0000u);
                ((u32*)&bx)[3] = (__float_as_uint(v1.z) >> 16) | (__float_as_uint(v1.w) & 0xFFFF0000u);
#pragma unroll
                for (int mt = 0; mt < 4; ++mt)
                    acc2[mt][n] = __builtin_amdgcn_mfma_f32_16x16x32_bf16(aA[mt], bx, acc2[mt][n], 0, 0, 0);
            }
        }
    };

    // prefetch tile 0
    float4 vc[8];
    {
        const float* xb = xg + (size_t)(b * C_ + 8*sm_) * SEQ_ + s_base + 4*sg_;
#pragma unroll
        for (int r = 0; r < 8; ++r) vc[r] = *(const float4*)(xb + (size_t)r * SEQ_);
    }

    float x2red[4];

    for (int tile = 0; tile < NT_; ++tile) {
        const int st = s_base + tile * TS_;
        __syncthreads();   // bar A: xsc free (GEMM1(t-1) done), alds(t-1) ready

        // ---- stage: split hi/lo, ||x||^2 partials ----
        {
            u16 H[8][4], L[8][4];
            float x2p[4] = {0.f,0.f,0.f,0.f};
#pragma unroll
            for (int r = 0; r < 8; ++r) {
                float fa[4] = {vc[r].x, vc[r].y, vc[r].z, vc[r].w};
#pragma unroll
                for (int i = 0; i < 4; ++i) {
                    float f = fa[i];
                    u32 bu = __float_as_uint(f);
                    u16 hh = (u16)(bu >> 16);                       // truncate
                    float fh = __uint_as_float((u32)hh << 16);
                    u16 ll = (u16)(__float_as_uint(f - fh) >> 16);  // exact residual, truncated
                    H[r][i] = hh; L[r][i] = ll;
                    x2p[i] = fmaf(f, f, x2p[i]);
                }
            }
            // prefetch next tile
            if (tile + 1 < NT_) {
                const float* xb = xg + (size_t)(b * C_ + 8*sm_) * SEQ_ + (st + TS_) + 4*sg_;
#pragma unroll
                for (int r = 0; r < 8; ++r) vc[r] = *(const float4*)(xb + (size_t)r * SEQ_);
            }
            // ||x||^2: reduce over sm_ (lane bits 0..3); result lands where softmax needs it:
            // lane (w,lg) ends with x2[16w+4lg+i] complete in x2p[i]
#pragma unroll
            for (int i = 0; i < 4; ++i) {
                float v = x2p[i];
                v += __shfl_xor(v, 1);
                v += __shfl_xor(v, 2);
                v += __shfl_xor(v, 4);
                v += __shfl_xor(v, 8);
                x2red[i] = v;
            }
            // x_sc [s][c] hi+lo, XOR-swizzled columns
#pragma unroll
            for (int i = 0; i < 4; ++i) {
                int s = 4*sg_ + i;
                u32 idx = (u32)(s * C_ + 8*sm_) ^ ((u32)(s & 15) << 3);
                uint4 hw, lw;
                hw.x = (u32)H[0][i] | ((u32)H[1][i] << 16);
                hw.y = (u32)H[2][i] | ((u32)H[3][i] << 16);
                hw.z = (u32)H[4][i] | ((u32)H[5][i] << 16);
                hw.w = (u32)H[6][i] | ((u32)H[7][i] << 16);
                lw.x = (u32)L[0][i] | ((u32)L[1][i] << 16);
                lw.y = (u32)L[2][i] | ((u32)L[3][i] << 16);
                lw.z = (u32)L[4][i] | ((u32)L[5][i] << 16);
                lw.w = (u32)L[6][i] | ((u32)L[7][i] << 16);
                *(uint4*)&xsc_h[idx] = hw;
                *(uint4*)&xsc_l[idx] = lw;
            }
        }
        // ---- GEMM2 of previous tile (overlaps staging; reads alds(t-1) + global) ----
        if (tile > 0) gemm2(st - TS_);
        __syncthreads();   // bar B: xsc(t) ready, alds free

        // ---- GEMM1: dot[s][k], hi+lo MFMA, streamed A-frags ----
        f32x4 d1[4] = {};
        {
            const int sA = 16*w + lk;
#pragma unroll
            for (int ks = 0; ks < 4; ++ks) {
                u32 idx = (u32)(sA * C_ + 8*lg + 32*ks) ^ ((u32)(sA & 15) << 3);
                bf16x8 ah = *(const bf16x8*)&xsc_h[idx];
                bf16x8 al = *(const bf16x8*)&xsc_l[idx];
#pragma unroll
                for (int nt = 0; nt < 4; ++nt) {
                    d1[nt] = __builtin_amdgcn_mfma_f32_16x16x32_bf16(ah, cwf[nt][ks], d1[nt], 0, 0, 0);
                    d1[nt] = __builtin_amdgcn_mfma_f32_16x16x32_bf16(al, cwf[nt][ks], d1[nt], 0, 0, 0);
                }
            }
        }

        // ---- softmax (in-register; sample s = 16w+4lg+r, k = lk+16nt) ----
        {
            float mx[4], pp[4][4], inv[4];
#pragma unroll
            for (int r = 0; r < 4; ++r) mx[r] = -1.0e30f;
#pragma unroll
            for (int nt = 0; nt < 4; ++nt)
#pragma unroll
              for (int r = 0; r < 4; ++r) {
                float lv = fmaf(smk[nt], x2red[r] - 2.0f * d1[nt][r], smc2k[nt]);
                lv = scrub(lv);
                pp[nt][r] = lv;
                mx[r] = fmaxf(mx[r], lv);
              }
#pragma unroll
            for (int r = 0; r < 4; ++r) {
                mx[r] = fmaxf(mx[r], __shfl_xor(mx[r], 1));
                mx[r] = fmaxf(mx[r], __shfl_xor(mx[r], 2));
                mx[r] = fmaxf(mx[r], __shfl_xor(mx[r], 4));
                mx[r] = fmaxf(mx[r], __shfl_xor(mx[r], 8));
            }
            float sum[4] = {0.f,0.f,0.f,0.f};
#pragma unroll
            for (int nt = 0; nt < 4; ++nt)
#pragma unroll
              for (int r = 0; r < 4; ++r) {
                float e = __expf(pp[nt][r] - mx[r]);
                pp[nt][r] = e;
                sum[r] += e;
              }
#pragma unroll
            for (int r = 0; r < 4; ++r) {
                sum[r] += __shfl_xor(sum[r], 1);
                sum[r] += __shfl_xor(sum[r], 2);
                sum[r] += __shfl_xor(sum[r], 4);
                sum[r] += __shfl_xor(sum[r], 8);
                inv[r] = 1.0f / sum[r];
            }
#pragma unroll
            for (int nt = 0; nt < 4; ++nt) {
                u16 q[4];
                float sloc = 0.f;
#pragma unroll
                for (int r = 0; r < 4; ++r) {
                    float a = pp[nt][r] * inv[r];
                    sloc += a;
                    q[r] = f2bf(a);
                }
                asacc[nt] += sloc;
                u64 pk = (u64)q[0] | ((u64)q[1] << 16) | ((u64)q[2] << 32) | ((u64)q[3] << 48);
                *(u64*)&alds[(lk + 16*nt) * TS_ + (((u32)(16*w + 4*lg)) ^ ((u32)(lk & 7) << 3))] = pk;
            }
        }
    }
    __syncthreads();
    gemm2(s_base + (NT_ - 1) * TS_);   // epilogue GEMM2 of last tile

    // ---- flush: e partials (once per block) ----
    float* eacc = ws + OFF_EACC;
#pragma unroll
    for (int mt = 0; mt < 4; ++mt)
#pragma unroll
      for (int n = 0; n < 2; ++n) {
        const int c = lk + 16*(2*w + n);
#pragma unroll
        for (int r = 0; r < 4; ++r) {
            int k = 16*mt + 4*lg + r;
            atomicAdd(&eacc[(b * K_ + k) * C_ + c], acc2[mt][n][r]);
        }
      }
#pragma unroll
    for (int nt = 0; nt < 4; ++nt) {
        float v = asacc[nt];
        v += __shfl_xor(v, 16);
        v += __shfl_xor(v, 32);
        if (lane < 16) atomicAdd(&ws[OFF_ASUM + b * K_ + lk + 16*nt], v);
    }
}

// ---------------- k2a: BN stats, one block per k ----------------
__global__ __launch_bounds__(256)
void k2a_stats(const float* __restrict__ cw,
               const float* __restrict__ bnw, const float* __restrict__ bnb,
               float* ws) {
    const int k = blockIdx.x;
    const int t = threadIdx.x;
    const int lane = t & 63, w = t >> 6;
    __shared__ float redS[4], redQ[4];
    const float* eacc = ws + OFF_EACC;
    const float* asum = ws + OFF_ASUM;
    float sv = 0.f, sq = 0.f;
#pragma unroll
    for (int u = t; u < 512; u += 256) {      // 512 float4 = 16b x 32
        int bb = u >> 5, c4 = u & 31;
        float a = asum[bb * K_ + k];
        float4 ev = *(const float4*)&eacc[(bb * K_ + k) * C_ + 4*c4];
        float4 cv = *(const float4*)&cw[k * C_ + 4*c4];
        float e0 = ev.x - a * cv.x, e1 = ev.y - a * cv.y;
        float e2 = ev.z - a * cv.z, e3 = ev.w - a * cv.w;
        sv += e0 + e1 + e2 + e3;
        sq += e0*e0 + e1*e1 + e2*e2 + e3*e3;
    }
#pragma unroll
    for (int m = 1; m < 64; m <<= 1) {
        sv += __shfl_xor(sv, m);
        sq += __shfl_xor(sq, m);
    }
    if (lane == 0) { redS[w] = sv; redQ[w] = sq; }
    __syncthreads();
    if (t == 0) {
        float s = redS[0]+redS[1]+redS[2]+redS[3];
        float q = redQ[0]+redQ[1]+redQ[2]+redQ[3];
        float mean = s * (1.f / 2048.f);
        float var  = q * (1.f / 2048.f) - mean * mean;
        float rstd = rsqrtf(fmaxf(var, 0.f) + 1e-5f);
        float g = bnw[k] * rstd;
        ws[OFF_BNS + k] = g;
        ws[OFF_BNB + k] = bnb[k] - mean * g;
    }
}

// ---------------- k2b: relu-mean + FC + sigmoid, one block per b ----------------
__global__ __launch_bounds__(256)
void k2b_fc(const float* __restrict__ cw,
            const float* __restrict__ fcw, const float* __restrict__ fcb,
            float* ws) {
    __shared__ float enorm_s[C_];
    __shared__ float red2[C_];
    const int b = blockIdx.x;
    const int t = threadIdx.x;
    const int c = t & 127, h = t >> 7;
    const float* eacc = ws + OFF_EACC;
    float s = 0.f;
    for (int kk = 0; kk < 32; ++kk) {
        int k = 32*h + kk;
        float e = eacc[(b * K_ + k) * C_ + c] - ws[OFF_ASUM + b * K_ + k] * cw[k * C_ + c];
        float bnv = e * ws[OFF_BNS + k] + ws[OFF_BNB + k];
        s += fminf(fmaxf(bnv, 0.f), 1.0e6f);
    }
    if (h) red2[c] = s;
    __syncthreads();
    if (!h) enorm_s[c] = (s + red2[c]) * (1.f / 64.f);
    __syncthreads();
    // FC: 2 threads per output c, split over inner dim
    float acc = 0.f;
    const float4* fw = (const float4*)&fcw[c * C_ + 64*h];
#pragma unroll
    for (int q = 0; q < 16; ++q) {
        float4 wv = fw[q];
        int ci = 64*h + 4*q;
        acc += enorm_s[ci] * wv.x + enorm_s[ci+1] * wv.y + enorm_s[ci+2] * wv.z + enorm_s[ci+3] * wv.w;
    }
    __syncthreads();
    if (h) red2[c] = acc;
    __syncthreads();
    if (!h) {
        float o = fcb[c] + acc + red2[c];
        ws[OFF_SCALE + b * C_ + c] = 1.f / (1.f + __expf(-o));
    }
}

// ---------------- k3: out = x * scale[b,c] ----------------
__global__ __launch_bounds__(256)
void k3_scale(const float4* __restrict__ xg, float4* __restrict__ outg,
              const float* __restrict__ ws) {
    const int bc = blockIdx.x;
    const float sc = ws[OFF_SCALE + bc];
    const float4* xr = xg + (size_t)bc * (SEQ_ / 4);
    float4* orow = outg + (size_t)bc * (SEQ_ / 4);
    const int t = threadIdx.x;
    for (int i = 0; i < SEQ_ / 4 / 256; ++i) {
        float4 v = xr[i * 256 + t];
        v.x *= sc; v.y *= sc; v.z *= sc; v.w *= sc;
        orow[i * 256 + t] = v;
    }
}

extern "C" void kernel_launch(void* const* d_in, const int* in_sizes, int n_in,
                              void* d_out, int out_size, void* d_ws, size_t ws_size,
                              hipStream_t stream) {
    const float* x   = (const float*)d_in[0];
    const float* cw  = (const float*)d_in[1];
    const float* sm  = (const float*)d_in[2];
    const float* bnw = (const float*)d_in[3];
    const float* bnb = (const float*)d_in[4];
    const float* fcw = (const float*)d_in[5];
    const float* fcb = (const float*)d_in[6];
    float* ws = (float*)d_ws;

    hipMemsetAsync(ws, 0, (size_t)(OFF_ASUM + B_ * K_) * sizeof(float), stream);
    k0_prep<<<1, 256, 0, stream>>>(cw, sm, ws);
    k1_encode<<<B_ * (SEQ_ / CHUNK_), 256, 0, stream>>>(x, cw, ws);
    k2a_stats<<<K_, 256, 0, stream>>>(cw, bnw, bnb, ws);
    k2b_fc<<<B_, 256, 0, stream>>>(cw, fcw, fcb, ws);
    k3_scale<<<B_ * C_, 256, 0, stream>>>((const float4*)x, (float4*)d_out, ws);
}

// Round 3
// 314.401 us; speedup vs baseline: 1.2306x; 1.2306x over previous
//
#include <hip/hip_runtime.h>

typedef unsigned int u32;
typedef unsigned short u16;
typedef unsigned long long u64;

typedef float f32x4 __attribute__((ext_vector_type(4)));
typedef short bf16x8 __attribute__((ext_vector_type(8)));

#define B_   16
#define C_   128
#define SEQ_ 16384
#define K_   64
#define TS_  64     // samples per tile
#define NT_  8      // tiles per block
#define CHUNK_ 512  // samples per block

// ---- workspace layout (float offsets) ----
constexpr int OFF_EACC = 0;            // [B][K][C] = 131072 floats (atomic accum)
constexpr int OFF_ASUM = 131072;       // [B][K]    = 1024
constexpr int OFF_BNS  = 132096;       // [K] bn scale  (k2a -> k2b)
constexpr int OFF_BNB  = 132160;       // [K] bn bias
constexpr int OFF_SM   = 136192;       // [K]
constexpr int OFF_SMC2 = 136256;       // [K] sm[k]*||cw_k||^2 (fp32-exact)
constexpr int OFF_SCALE= 136320;       // [B][C] = 2048

__device__ __forceinline__ u16 f2bf(float f) {
    u32 b = __float_as_uint(f);
    return (u16)((b + 0x7FFFu + ((b >> 16) & 1u)) >> 16);   // RNE
}
__device__ __forceinline__ float scrub(float v) {
    return fminf(fmaxf(v, -1.0e4f), 1.0e4f);
}

// ---------------- k0: prep tables ----------------
__global__ void k0_prep(const float* __restrict__ cw, const float* __restrict__ sm,
                        float* __restrict__ ws) {
    const int t = threadIdx.x;
    if (t < K_) {
        float s2 = 0.f;
        for (int c = 0; c < C_; ++c) { float f = cw[t * C_ + c]; s2 += f * f; }
        float smv = sm[t];
        ws[OFF_SM + t] = smv;
        ws[OFF_SMC2 + t] = smv * s2;
    }
}

// ---------------- k1: MFMA soft-assign encode + aggregate ----------------
// grid = 512 blocks, 256 threads (4 waves), 2 blocks/CU (LDS 76KB)
// 2 barriers/tile software pipeline:
//   phase2(t): stage xsc(t)+xcs[t&1](t) + prefetch(t+1) + GEMM2(t-1) from xcs[(t-1)&1]
//   phase1(t): GEMM1(t) + softmax(t) + alds write
// launch_bounds (256,2): VGPR cap 256 -> NO SPILL (round-2 lesson: (256,3) spilled,
// WRITE_SIZE 25->173MB, k1 became scratch-BW-bound)
__global__ __launch_bounds__(256, 2)
void k1_encode(const float* __restrict__ xg, const float* __restrict__ cwg, float* ws) {
    __shared__ __align__(16) u16 xsc_h[TS_ * C_];   // [s][c] hi, XOR ((s&15)<<3) on c-units
    __shared__ __align__(16) u16 xsc_l[TS_ * C_];   // [s][c] lo
    __shared__ __align__(16) u16 xcs[2][C_ * 72];   // [c][s] hi, stride 72, XOR ((c>>3)&7)<<3, dbuf
    __shared__ __align__(16) u16 alds[K_ * TS_];    // [k][s], XOR ((k&7)<<3) on s

    const int t    = threadIdx.x;
    const int lane = t & 63;
    const int w    = t >> 6;
    const int lk   = lane & 15;
    const int lg   = lane >> 4;
    const int b      = blockIdx.x >> 5;
    const int s_base = (blockIdx.x & 31) * CHUNK_;

    // codeword fragments (GEMM1 B-operand), bf16 RNE, register-resident
    bf16x8 cwf[4][4];
#pragma unroll
    for (int nt = 0; nt < 4; ++nt)
#pragma unroll
      for (int ks = 0; ks < 4; ++ks) {
        const float* p = cwg + (size_t)(lk + 16*nt) * C_ + 8*lg + 32*ks;
        float4 v0 = *(const float4*)p;
        float4 v1 = *(const float4*)(p + 4);
        bf16x8 f;
        f[0]=(short)f2bf(v0.x); f[1]=(short)f2bf(v0.y); f[2]=(short)f2bf(v0.z); f[3]=(short)f2bf(v0.w);
        f[4]=(short)f2bf(v1.x); f[5]=(short)f2bf(v1.y); f[6]=(short)f2bf(v1.z); f[7]=(short)f2bf(v1.w);
        cwf[nt][ks] = f;
      }
    float smk[4], smc2k[4];
#pragma unroll
    for (int nt = 0; nt < 4; ++nt) {
        smk[nt]   = ws[OFF_SM   + lk + 16*nt];
        smc2k[nt] = ws[OFF_SMC2 + lk + 16*nt];
    }

    f32x4 acc2[4][2] = {};              // GEMM2 accum, persists across all tiles
    float asacc[4] = {0.f,0.f,0.f,0.f};

    const int sm_ = t & 15;   // staging: c0 = 8*sm_
    const int sg_ = t >> 4;   // staging: s0 = 4*sg_

    // GEMM2: A = alds rows, B = xcs[pb] rows (x^T bf16-hi, staged)
    auto gemm2 = [&](int pb) {
#pragma unroll
        for (int ss = 0; ss < 2; ++ss) {
            bf16x8 aA[4];
#pragma unroll
            for (int mt = 0; mt < 4; ++mt)
                aA[mt] = *(const bf16x8*)&alds[(lk + 16*mt) * TS_ + ((8*lg + 32*ss) ^ ((lk & 7) << 3))];
#pragma unroll
            for (int n = 0; n < 2; ++n) {
                const int c = lk + 16*(2*w + n);
                bf16x8 bx = *(const bf16x8*)&xcs[pb][c * 72 + ((8*lg + 32*ss) ^ (((c >> 3) & 7) << 3))];
#pragma unroll
                for (int mt = 0; mt < 4; ++mt)
                    acc2[mt][n] = __builtin_amdgcn_mfma_f32_16x16x32_bf16(aA[mt], bx, acc2[mt][n], 0, 0, 0);
            }
        }
    };

    // prefetch tile 0
    float4 vc[8];
    {
        const float* xb = xg + (size_t)(b * C_ + 8*sm_) * SEQ_ + s_base + 4*sg_;
#pragma unroll
        for (int r = 0; r < 8; ++r) vc[r] = *(const float4*)(xb + (size_t)r * SEQ_);
    }

    float x2red[4];

    for (int tile = 0; tile < NT_; ++tile) {
        const int st = s_base + tile * TS_;
        const int cur = tile & 1;
        __syncthreads();   // bar A: xsc free (GEMM1(t-1) done), alds(t-1) ready

        // ---- stage: split hi/lo, ||x||^2 partials ----
        {
            u16 H[8][4], L[8][4];
            float x2p[4] = {0.f,0.f,0.f,0.f};
#pragma unroll
            for (int r = 0; r < 8; ++r) {
                float fa[4] = {vc[r].x, vc[r].y, vc[r].z, vc[r].w};
#pragma unroll
                for (int i = 0; i < 4; ++i) {
                    float f = fa[i];
                    u32 bu = __float_as_uint(f);
                    u16 hh = (u16)(bu >> 16);                       // truncate
                    float fh = __uint_as_float((u32)hh << 16);
                    u16 ll = (u16)(__float_as_uint(f - fh) >> 16);  // exact residual, truncated
                    H[r][i] = hh; L[r][i] = ll;
                    x2p[i] = fmaf(f, f, x2p[i]);
                }
            }
            // prefetch next tile
            if (tile + 1 < NT_) {
                const float* xb = xg + (size_t)(b * C_ + 8*sm_) * SEQ_ + (st + TS_) + 4*sg_;
#pragma unroll
                for (int r = 0; r < 8; ++r) vc[r] = *(const float4*)(xb + (size_t)r * SEQ_);
            }
            // ||x||^2: reduce over sm_ (lane bits 0..3); lane (w,lg) ends with
            // x2[16w+4lg+i] complete in x2red[i] (exactly where softmax needs it)
#pragma unroll
            for (int i = 0; i < 4; ++i) {
                float v = x2p[i];
                v += __shfl_xor(v, 1);
                v += __shfl_xor(v, 2);
                v += __shfl_xor(v, 4);
                v += __shfl_xor(v, 8);
                x2red[i] = v;
            }
            // x_cs [c][s] hi, stride 72 (144B rotates banks), dbuf cur
#pragma unroll
            for (int r = 0; r < 8; ++r) {
                int c = 8*sm_ + r;
                u64 pk = (u64)H[r][0] | ((u64)H[r][1] << 16) | ((u64)H[r][2] << 32) | ((u64)H[r][3] << 48);
                *(u64*)&xcs[cur][c * 72 + ((4*sg_) ^ ((sm_ & 7) << 3))] = pk;
            }
            // x_sc [s][c] hi+lo, XOR-swizzled columns
#pragma unroll
            for (int i = 0; i < 4; ++i) {
                int s = 4*sg_ + i;
                u32 idx = (u32)(s * C_ + 8*sm_) ^ ((u32)(s & 15) << 3);
                uint4 hw, lw;
                hw.x = (u32)H[0][i] | ((u32)H[1][i] << 16);
                hw.y = (u32)H[2][i] | ((u32)H[3][i] << 16);
                hw.z = (u32)H[4][i] | ((u32)H[5][i] << 16);
                hw.w = (u32)H[6][i] | ((u32)H[7][i] << 16);
                lw.x = (u32)L[0][i] | ((u32)L[1][i] << 16);
                lw.y = (u32)L[2][i] | ((u32)L[3][i] << 16);
                lw.z = (u32)L[4][i] | ((u32)L[5][i] << 16);
                lw.w = (u32)L[6][i] | ((u32)L[7][i] << 16);
                *(uint4*)&xsc_h[idx] = hw;
                *(uint4*)&xsc_l[idx] = lw;
            }
        }
        // ---- GEMM2 of previous tile (overlaps staging; reads alds(t-1) + xcs[1-cur]) ----
        if (tile > 0) gemm2(cur ^ 1);
        __syncthreads();   // bar B: xsc(t)/xcs[cur](t) ready, alds free

        // ---- GEMM1: dot[s][k], hi+lo MFMA, streamed A-frags ----
        f32x4 d1[4] = {};
        {
            const int sA = 16*w + lk;
#pragma unroll
            for (int ks = 0; ks < 4; ++ks) {
                u32 idx = (u32)(sA * C_ + 8*lg + 32*ks) ^ ((u32)(sA & 15) << 3);
                bf16x8 ah = *(const bf16x8*)&xsc_h[idx];
                bf16x8 al = *(const bf16x8*)&xsc_l[idx];
#pragma unroll
                for (int nt = 0; nt < 4; ++nt) {
                    d1[nt] = __builtin_amdgcn_mfma_f32_16x16x32_bf16(ah, cwf[nt][ks], d1[nt], 0, 0, 0);
                    d1[nt] = __builtin_amdgcn_mfma_f32_16x16x32_bf16(al, cwf[nt][ks], d1[nt], 0, 0, 0);
                }
            }
        }

        // ---- softmax (in-register; sample s = 16w+4lg+r, k = lk+16nt) ----
        {
            float mx[4], pp[4][4], inv[4];
#pragma unroll
            for (int r = 0; r < 4; ++r) mx[r] = -1.0e30f;
#pragma unroll
            for (int nt = 0; nt < 4; ++nt)
#pragma unroll
              for (int r = 0; r < 4; ++r) {
                float lv = fmaf(smk[nt], x2red[r] - 2.0f * d1[nt][r], smc2k[nt]);
                lv = scrub(lv);
                pp[nt][r] = lv;
                mx[r] = fmaxf(mx[r], lv);
              }
#pragma unroll
            for (int r = 0; r < 4; ++r) {
                mx[r] = fmaxf(mx[r], __shfl_xor(mx[r], 1));
                mx[r] = fmaxf(mx[r], __shfl_xor(mx[r], 2));
                mx[r] = fmaxf(mx[r], __shfl_xor(mx[r], 4));
                mx[r] = fmaxf(mx[r], __shfl_xor(mx[r], 8));
            }
            float sum[4] = {0.f,0.f,0.f,0.f};
#pragma unroll
            for (int nt = 0; nt < 4; ++nt)
#pragma unroll
              for (int r = 0; r < 4; ++r) {
                float e = __expf(pp[nt][r] - mx[r]);
                pp[nt][r] = e;
                sum[r] += e;
              }
#pragma unroll
            for (int r = 0; r < 4; ++r) {
                sum[r] += __shfl_xor(sum[r], 1);
                sum[r] += __shfl_xor(sum[r], 2);
                sum[r] += __shfl_xor(sum[r], 4);
                sum[r] += __shfl_xor(sum[r], 8);
                inv[r] = 1.0f / sum[r];
            }
#pragma unroll
            for (int nt = 0; nt < 4; ++nt) {
                u16 q[4];
                float sloc = 0.f;
#pragma unroll
                for (int r = 0; r < 4; ++r) {
                    float a = pp[nt][r] * inv[r];
                    sloc += a;
                    q[r] = f2bf(a);
                }
                asacc[nt] += sloc;
                u64 pk = (u64)q[0] | ((u64)q[1] << 16) | ((u64)q[2] << 32) | ((u64)q[3] << 48);
                *(u64*)&alds[(lk + 16*nt) * TS_ + (((u32)(16*w + 4*lg)) ^ ((u32)(lk & 7) << 3))] = pk;
            }
        }
    }
    __syncthreads();
    gemm2((NT_ - 1) & 1);   // epilogue GEMM2 of last tile

    // ---- flush: e partials (once per block) ----
    float* eacc = ws + OFF_EACC;
#pragma unroll
    for (int mt = 0; mt < 4; ++mt)
#pragma unroll
      for (int n = 0; n < 2; ++n) {
        const int c = lk + 16*(2*w + n);
#pragma unroll
        for (int r = 0; r < 4; ++r) {
            int k = 16*mt + 4*lg + r;
            atomicAdd(&eacc[(b * K_ + k) * C_ + c], acc2[mt][n][r]);
        }
      }
#pragma unroll
    for (int nt = 0; nt < 4; ++nt) {
        float v = asacc[nt];
        v += __shfl_xor(v, 16);
        v += __shfl_xor(v, 32);
        if (lane < 16) atomicAdd(&ws[OFF_ASUM + b * K_ + lk + 16*nt], v);
    }
}

// ---------------- k2a: BN stats, one block per k ----------------
__global__ __launch_bounds__(256)
void k2a_stats(const float* __restrict__ cw,
               const float* __restrict__ bnw, const float* __restrict__ bnb,
               float* ws) {
    const int k = blockIdx.x;
    const int t = threadIdx.x;
    const int lane = t & 63, w = t >> 6;
    __shared__ float redS[4], redQ[4];
    const float* eacc = ws + OFF_EACC;
    const float* asum = ws + OFF_ASUM;
    float sv = 0.f, sq = 0.f;
#pragma unroll
    for (int u = t; u < 512; u += 256) {      // 512 float4 = 16b x 32
        int bb = u >> 5, c4 = u & 31;
        float a = asum[bb * K_ + k];
        float4 ev = *(const float4*)&eacc[(bb * K_ + k) * C_ + 4*c4];
        float4 cv = *(const float4*)&cw[k * C_ + 4*c4];
        float e0 = ev.x - a * cv.x, e1 = ev.y - a * cv.y;
        float e2 = ev.z - a * cv.z, e3 = ev.w - a * cv.w;
        sv += e0 + e1 + e2 + e3;
        sq += e0*e0 + e1*e1 + e2*e2 + e3*e3;
    }
#pragma unroll
    for (int m = 1; m < 64; m <<= 1) {
        sv += __shfl_xor(sv, m);
        sq += __shfl_xor(sq, m);
    }
    if (lane == 0) { redS[w] = sv; redQ[w] = sq; }
    __syncthreads();
    if (t == 0) {
        float s = redS[0]+redS[1]+redS[2]+redS[3];
        float q = redQ[0]+redQ[1]+redQ[2]+redQ[3];
        float mean = s * (1.f / 2048.f);
        float var  = q * (1.f / 2048.f) - mean * mean;
        float rstd = rsqrtf(fmaxf(var, 0.f) + 1e-5f);
        float g = bnw[k] * rstd;
        ws[OFF_BNS + k] = g;
        ws[OFF_BNB + k] = bnb[k] - mean * g;
    }
}

// ---------------- k2b: relu-mean + FC + sigmoid, one block per b ----------------
__global__ __launch_bounds__(256)
void k2b_fc(const float* __restrict__ cw,
            const float* __restrict__ fcw, const float* __restrict__ fcb,
            float* ws) {
    __shared__ float enorm_s[C_];
    __shared__ float red2[C_];
    const int b = blockIdx.x;
    const int t = threadIdx.x;
    const int c = t & 127, h = t >> 7;
    const float* eacc = ws + OFF_EACC;
    float s = 0.f;
    for (int kk = 0; kk < 32; ++kk) {
        int k = 32*h + kk;
        float e = eacc[(b * K_ + k) * C_ + c] - ws[OFF_ASUM + b * K_ + k] * cw[k * C_ + c];
        float bnv = e * ws[OFF_BNS + k] + ws[OFF_BNB + k];
        s += fminf(fmaxf(bnv, 0.f), 1.0e6f);
    }
    if (h) red2[c] = s;
    __syncthreads();
    if (!h) enorm_s[c] = (s + red2[c]) * (1.f / 64.f);
    __syncthreads();
    // FC: 2 threads per output c, split over inner dim
    float acc = 0.f;
    const float4* fw = (const float4*)&fcw[c * C_ + 64*h];
#pragma unroll
    for (int q = 0; q < 16; ++q) {
        float4 wv = fw[q];
        int ci = 64*h + 4*q;
        acc += enorm_s[ci] * wv.x + enorm_s[ci+1] * wv.y + enorm_s[ci+2] * wv.z + enorm_s[ci+3] * wv.w;
    }
    __syncthreads();
    if (h) red2[c] = acc;
    __syncthreads();
    if (!h) {
        float o = fcb[c] + acc + red2[c];
        ws[OFF_SCALE + b * C_ + c] = 1.f / (1.f + __expf(-o));
    }
}

// ---------------- k3: out = x * scale[b,c] ----------------
__global__ __launch_bounds__(256)
void k3_scale(const float4* __restrict__ xg, float4* __restrict__ outg,
              const float* __restrict__ ws) {
    const int bc = blockIdx.x;
    const float sc = ws[OFF_SCALE + bc];
    const float4* xr = xg + (size_t)bc * (SEQ_ / 4);
    float4* orow = outg + (size_t)bc * (SEQ_ / 4);
    const int t = threadIdx.x;
    for (int i = 0; i < SEQ_ / 4 / 256; ++i) {
        float4 v = xr[i * 256 + t];
        v.x *= sc; v.y *= sc; v.z *= sc; v.w *= sc;
        orow[i * 256 + t] = v;
    }
}

extern "C" void kernel_launch(void* const* d_in, const int* in_sizes, int n_in,
                              void* d_out, int out_size, void* d_ws, size_t ws_size,
                              hipStream_t stream) {
    const float* x   = (const float*)d_in[0];
    const float* cw  = (const float*)d_in[1];
    const float* sm  = (const float*)d_in[2];
    const float* bnw = (const float*)d_in[3];
    const float* bnb = (const float*)d_in[4];
    const float* fcw = (const float*)d_in[5];
    const float* fcb = (const float*)d_in[6];
    float* ws = (float*)d_ws;

    hipMemsetAsync(ws, 0, (size_t)(OFF_ASUM + B_ * K_) * sizeof(float), stream);
    k0_prep<<<1, 256, 0, stream>>>(cw, sm, ws);
    k1_encode<<<B_ * (SEQ_ / CHUNK_), 256, 0, stream>>>(x, cw, ws);
    k2a_stats<<<K_, 256, 0, stream>>>(cw, bnw, bnb, ws);
    k2b_fc<<<B_, 256, 0, stream>>>(cw, fcw, fcb, ws);
    k3_scale<<<B_ * C_, 256, 0, stream>>>((const float4*)x, (float4*)d_out, ws);
}